// Round 10
// baseline (1049.927 us; speedup 1.0000x reference)
//
#include <hip/hip_runtime.h>
#include <hip/hip_bf16.h>
#include <cstdint>

constexpr int Mx = 8192;
constexpr int Kx = 4096;
constexpr int Nx = 16384;
constexpr long W_ELEMS = (long)Nx * Kx;      // 67108864
constexpr long X_ELEMS = (long)Mx * Kx;      // 33554432
constexpr int KB = Kx / 2;                   // 2048 packed fp4 bytes per row

typedef int v4i __attribute__((ext_vector_type(4)));
typedef int v8i __attribute__((ext_vector_type(8)));
typedef float v16f __attribute__((ext_vector_type(16)));

#define GLOBAL_AS(p) ((const __attribute__((address_space(1))) void*)(p))
#define LDS_AS(p)    ((__attribute__((address_space(3))) void*)(p))

template <int P> struct IC { static constexpr int value = P; };

// ---------------- Pass 1: sum |W| (deterministic two-level tree) ----------------
__global__ __launch_bounds__(256) void absum_kernel(const float4* __restrict__ W4,
                                                    double* __restrict__ partials) {
    int t = threadIdx.x;
    long base = (long)blockIdx.x * 8192;
    double s = 0.0;
#pragma unroll 4
    for (int i = 0; i < 32; ++i) {
        float4 v = W4[base + (long)i * 256 + t];
        s += (double)fabsf(v.x) + (double)fabsf(v.y) +
             (double)fabsf(v.z) + (double)fabsf(v.w);
    }
    __shared__ double sm[256];
    sm[t] = s;
    __syncthreads();
    for (int off = 128; off > 0; off >>= 1) {
        if (t < off) sm[t] += sm[t + off];
        __syncthreads();
    }
    if (t == 0) partials[blockIdx.x] = sm[0];
}

__global__ __launch_bounds__(256) void finalize_kernel(const double* __restrict__ partials,
                                                       float* __restrict__ thr) {
    int t = threadIdx.x;
    double s = 0.0;
#pragma unroll
    for (int i = 0; i < 8; ++i) s += partials[(long)i * 256 + t];
    __shared__ double sm[256];
    sm[t] = s;
    __syncthreads();
    for (int off = 128; off > 0; off >>= 1) {
        if (t < off) sm[t] += sm[t + off];
        __syncthreads();
    }
    if (t == 0) {
        double gamma = sm[0] / (double)W_ELEMS + 1e-6;
        *thr = (float)(0.5 * gamma);
    }
}

// fp4 e2m1 encode of ternary: +1 -> 0x2, -1 -> 0xA, 0 -> 0x0
__device__ __forceinline__ uint32_t enc_t(float v, float thr) {
    return (fabsf(v) > thr) ? ((v > 0.f) ? 0x2u : 0xAu) : 0x0u;
}

__device__ __forceinline__ uint32_t pack8(float4 a, float4 b, float thr) {
    return enc_t(a.x, thr)        | (enc_t(a.y, thr) << 4)  |
          (enc_t(a.z, thr) << 8)  | (enc_t(a.w, thr) << 12) |
          (enc_t(b.x, thr) << 16) | (enc_t(b.y, thr) << 20) |
          (enc_t(b.z, thr) << 24) | (enc_t(b.w, thr) << 28);
}

// ---------------- Pass 2: quantize W -> packed fp4 (32 elems/thread) -----------
__global__ __launch_bounds__(256) void quantw_kernel(const float4* __restrict__ W4,
                                                     uint4* __restrict__ out,
                                                     const float* __restrict__ thrp) {
    float thr = *thrp;
    long gt = (long)blockIdx.x * 256 + threadIdx.x;
    uint32_t d0 = pack8(W4[gt * 8 + 0], W4[gt * 8 + 1], thr);
    uint32_t d1 = pack8(W4[gt * 8 + 2], W4[gt * 8 + 3], thr);
    uint32_t d2 = pack8(W4[gt * 8 + 4], W4[gt * 8 + 5], thr);
    uint32_t d3 = pack8(W4[gt * 8 + 6], W4[gt * 8 + 7], thr);
    out[gt] = make_uint4(d0, d1, d2, d3);
}

// ---------------- Pass 3: binarize x -> packed fp4 sign ------------------------
__global__ __launch_bounds__(256) void quantx_kernel(const float4* __restrict__ X4,
                                                     uint4* __restrict__ out) {
    long gt = (long)blockIdx.x * 256 + threadIdx.x;
    uint32_t d0 = pack8(X4[gt * 8 + 0], X4[gt * 8 + 1], 0.f);
    uint32_t d1 = pack8(X4[gt * 8 + 2], X4[gt * 8 + 3], 0.f);
    uint32_t d2 = pack8(X4[gt * 8 + 4], X4[gt * 8 + 5], 0.f);
    uint32_t d3 = pack8(X4[gt * 8 + 6], X4[gt * 8 + 7], 0.f);
    out[gt] = make_uint4(d0, d1, d2, d3);
}

// ---------------- Pass 4: fp4 GEMM, 256^2 tile, mfma_scale 32x32x64 ------------
// r9 schedule (single barrier per half-phase, proven absmax 0) re-dimensioned
// to 16 waves x (64x64 output) on the SAME 256^2 tile:
//   acc = 64 regs/wave (vs 128) -> target 16 waves/CU (4/SIMD) so that waves
//   genuinely overlap: one wave's MFMA cluster runs while other waves' ds_read
//   bursts drain (TLP -- the mechanism 2-waves/SIMD lockstep could not give).
// Per half-phase per wave: 4 frag reads (2A+2B), 4 MFMAs; per CU totals
// unchanged (64 MFMA / 64 reads).  Staging: 1024 thr = 1 chunk (16 B)/thread
// per unit; unit = 16 KB slot; ring 8; lead 5; vmcnt 3/2/0 (1 load per stage).
// WAR/data-ready proofs identical to r9 (slot distance 4..6 mod 8; per-wave
// vmcnt precedes barrier arrival).
__global__ __launch_bounds__(1024) void gemm_fp4(const uint8_t* __restrict__ A,
                                                 const uint8_t* __restrict__ B,
                                                 float* __restrict__ C) {
    __shared__ __align__(16) uint8_t smem[8 * 16384];   // 128 KiB

    const int t = threadIdx.x;
    const int l = t & 63;
    const int wid = t >> 6;           // 0..15
    const int wm = wid >> 2;          // 0..3
    const int wn = wid & 3;           // 0..3
    const int lr = l & 31;            // row within 32
    const int lh = l >> 5;            // k-chunk selector

    // Bijective XCD swizzle: 2048 wgs % 8 == 0.
    int wg = blockIdx.x;
    int sw = (wg & 7) * 256 + (wg >> 3);
    int bm = sw & 31;                 // 32 M-tiles
    int bn = sw >> 5;                 // 64 N-tiles
    const long m0 = (long)bm * 256;
    const long n0 = (long)bn * 256;

    // Staging: unit = 1024 chunks of 16B, thread t takes chunk t.
    // Phys chunk cp holds row r = cp>>2, logical col c = (cp&3)^((r>>1)&3).
    const int r0s = t >> 2;           // 0..255
    const int cb0 = (((t & 3) ^ ((r0s >> 1) & 3)) << 4);
    const int voff = r0s * KB + cb0;             // shared by A and B panels
    const uint8_t* Abase = A + m0 * (long)KB;    // uniform -> SGPR
    const uint8_t* Bbase = B + n0 * (long)KB;    // uniform -> SGPR
    const int lo = t * 16;

    // ds_read offsets (swizzled, r2-proven XOR), per k-half h: c = h*2 + lh.
    auto swz = [](int r, int c) {
        return r * 64 + ((c ^ ((r >> 1) & 3)) << 4);
    };
    int offA[2][2], offB[2][2];
#pragma unroll
    for (int h = 0; h < 2; ++h) {
#pragma unroll
        for (int mt = 0; mt < 2; ++mt)
            offA[h][mt] = swz(wm * 64 + mt * 32 + lr, h * 2 + lh);
#pragma unroll
        for (int nt = 0; nt < 2; ++nt)
            offB[h][nt] = swz(wn * 64 + nt * 32 + lr, h * 2 + lh);
    }

    v16f acc[2][2] = {};   // 64 regs (AGPR-eligible)

    // Prologue: issue units 0..4 (1 load each); wait units 0,1 landed.
#pragma unroll
    for (int j = 0; j < 5; ++j) {
        const uint8_t* s = (j & 1) ? Bbase : Abase;
        __builtin_amdgcn_global_load_lds(GLOBAL_AS(s + (j >> 1) * 64 + voff),
                                         LDS_AS(smem + j * 16384 + lo), 16, 0, 0);
    }
    asm volatile("s_waitcnt vmcnt(3)" ::: "memory");
    asm volatile("s_barrier" ::: "memory");

#pragma unroll 2
    for (int tau = 0; tau < 32; ++tau) {
        auto phase = [&](auto hc) {
            constexpr int h = decltype(hc)::value;
            const int sA = (2 * tau) & 7;
            const int sB = sA + 1;
            // Fragments in low half of v8i; high half undef (HW reads only
            // regs 0..3 for FMT=fp4 -- r4/r5/r6 exactness proves it).
            v8i a0, a1, b0, b1;
            {
                v4i v = *(const v4i*)(smem + sA * 16384 + offA[h][0]);
                a0 = __builtin_shufflevector(v, v, 0, 1, 2, 3, -1, -1, -1, -1);
            }
            {
                v4i v = *(const v4i*)(smem + sA * 16384 + offA[h][1]);
                a1 = __builtin_shufflevector(v, v, 0, 1, 2, 3, -1, -1, -1, -1);
            }
            {
                v4i v = *(const v4i*)(smem + sB * 16384 + offB[h][0]);
                b0 = __builtin_shufflevector(v, v, 0, 1, 2, 3, -1, -1, -1, -1);
            }
            {
                v4i v = *(const v4i*)(smem + sB * 16384 + offB[h][1]);
                b1 = __builtin_shufflevector(v, v, 0, 1, 2, 3, -1, -1, -1, -1);
            }
            // Stage unit j = 2*tau + h + 5 into slot j&7 (freed 2 barriers ago).
            {
                int j = 2 * tau + h + 5;
                if (j < 64) {
                    const uint8_t* s = (j & 1) ? Bbase : Abase;
                    __builtin_amdgcn_global_load_lds(GLOBAL_AS(s + (j >> 1) * 64 + voff),
                                                     LDS_AS(smem + (j & 7) * 16384 + lo), 16, 0, 0);
                }
            }
            __builtin_amdgcn_s_setprio(1);
            acc[0][0] = __builtin_amdgcn_mfma_scale_f32_32x32x64_f8f6f4(
                a0, b0, acc[0][0], 4, 4, 0, 0x7F7F7F7F, 0, 0x7F7F7F7F);
            acc[0][1] = __builtin_amdgcn_mfma_scale_f32_32x32x64_f8f6f4(
                a0, b1, acc[0][1], 4, 4, 0, 0x7F7F7F7F, 0, 0x7F7F7F7F);
            acc[1][0] = __builtin_amdgcn_mfma_scale_f32_32x32x64_f8f6f4(
                a1, b0, acc[1][0], 4, 4, 0, 0x7F7F7F7F, 0, 0x7F7F7F7F);
            acc[1][1] = __builtin_amdgcn_mfma_scale_f32_32x32x64_f8f6f4(
                a1, b1, acc[1][1], 4, 4, 0, 0x7F7F7F7F, 0, 0x7F7F7F7F);
            __builtin_amdgcn_s_setprio(0);
            if constexpr (h == 1) {
                if (tau <= 28)      asm volatile("s_waitcnt vmcnt(3)" ::: "memory");
                else if (tau == 29) asm volatile("s_waitcnt vmcnt(2)" ::: "memory");
                else if (tau == 30) asm volatile("s_waitcnt vmcnt(0)" ::: "memory");
            }
            asm volatile("s_barrier" ::: "memory");
        };
        phase(IC<0>{});
        phase(IC<1>{});
    }

    // Epilogue: 32x32 C/D layout col = lane&31, row = (reg&3)+8*(reg>>2)+4*(lane>>5).
#pragma unroll
    for (int mt = 0; mt < 2; ++mt) {
        long rbase = m0 + wm * 64 + mt * 32 + 4 * lh;
#pragma unroll
        for (int nt = 0; nt < 2; ++nt) {
            long gcol = n0 + wn * 64 + nt * 32 + lr;
#pragma unroll
            for (int r = 0; r < 16; ++r) {
                long grow = rbase + (r & 3) + 8 * (r >> 2);
                C[grow * Nx + gcol] = acc[mt][nt][r];
            }
        }
    }
}

extern "C" void kernel_launch(void* const* d_in, const int* in_sizes, int n_in,
                              void* d_out, int out_size, void* d_ws, size_t ws_size,
                              hipStream_t stream) {
    const float* x = (const float*)d_in[0];
    const float* weight = (const float*)d_in[1];
    float* out = (float*)d_out;

    // Workspace: xq 16 MB | wq 32 MB | partials 16 KB | thr
    uint8_t* xq = (uint8_t*)d_ws;
    uint8_t* wq = xq + X_ELEMS / 2;
    double* partials = (double*)((char*)d_ws + X_ELEMS / 2 + W_ELEMS / 2);
    float* thr = (float*)((char*)d_ws + X_ELEMS / 2 + W_ELEMS / 2 + 2048 * sizeof(double));

    absum_kernel<<<2048, 256, 0, stream>>>((const float4*)weight, partials);
    finalize_kernel<<<1, 256, 0, stream>>>(partials, thr);
    quantw_kernel<<<8192, 256, 0, stream>>>((const float4*)weight, (uint4*)wq, thr);
    quantx_kernel<<<4096, 256, 0, stream>>>((const float4*)x, (uint4*)xq);
    gemm_fp4<<<2048, 1024, 0, stream>>>(xq, wq, out);
}

// Round 11
// 1049.047 us; speedup vs baseline: 1.0008x; 1.0008x over previous
//
#include <hip/hip_runtime.h>
#include <hip/hip_bf16.h>
#include <cstdint>

constexpr int Mx = 8192;
constexpr int Kx = 4096;
constexpr int Nx = 16384;
constexpr long W_ELEMS = (long)Nx * Kx;      // 67108864
constexpr long X_ELEMS = (long)Mx * Kx;      // 33554432
constexpr int KB = Kx / 2;                   // 2048 packed fp4 bytes per row

typedef int v4i __attribute__((ext_vector_type(4)));
typedef int v8i __attribute__((ext_vector_type(8)));
typedef float v16f __attribute__((ext_vector_type(16)));

#define GLOBAL_AS(p) ((const __attribute__((address_space(1))) void*)(p))
#define LDS_AS(p)    ((__attribute__((address_space(3))) void*)(p))

template <int P> struct IC { static constexpr int value = P; };

// ---------------- Pass 1: sum |W| (deterministic two-level tree) ----------------
__global__ __launch_bounds__(256) void absum_kernel(const float4* __restrict__ W4,
                                                    double* __restrict__ partials) {
    int t = threadIdx.x;
    long base = (long)blockIdx.x * 8192;
    double s = 0.0;
#pragma unroll 4
    for (int i = 0; i < 32; ++i) {
        float4 v = W4[base + (long)i * 256 + t];
        s += (double)fabsf(v.x) + (double)fabsf(v.y) +
             (double)fabsf(v.z) + (double)fabsf(v.w);
    }
    __shared__ double sm[256];
    sm[t] = s;
    __syncthreads();
    for (int off = 128; off > 0; off >>= 1) {
        if (t < off) sm[t] += sm[t + off];
        __syncthreads();
    }
    if (t == 0) partials[blockIdx.x] = sm[0];
}

__global__ __launch_bounds__(256) void finalize_kernel(const double* __restrict__ partials,
                                                       float* __restrict__ thr) {
    int t = threadIdx.x;
    double s = 0.0;
#pragma unroll
    for (int i = 0; i < 8; ++i) s += partials[(long)i * 256 + t];
    __shared__ double sm[256];
    sm[t] = s;
    __syncthreads();
    for (int off = 128; off > 0; off >>= 1) {
        if (t < off) sm[t] += sm[t + off];
        __syncthreads();
    }
    if (t == 0) {
        double gamma = sm[0] / (double)W_ELEMS + 1e-6;
        *thr = (float)(0.5 * gamma);
    }
}

// fp4 e2m1 encode of ternary: +1 -> 0x2, -1 -> 0xA, 0 -> 0x0
__device__ __forceinline__ uint32_t enc_t(float v, float thr) {
    return (fabsf(v) > thr) ? ((v > 0.f) ? 0x2u : 0xAu) : 0x0u;
}

__device__ __forceinline__ uint32_t pack8(float4 a, float4 b, float thr) {
    return enc_t(a.x, thr)        | (enc_t(a.y, thr) << 4)  |
          (enc_t(a.z, thr) << 8)  | (enc_t(a.w, thr) << 12) |
          (enc_t(b.x, thr) << 16) | (enc_t(b.y, thr) << 20) |
          (enc_t(b.z, thr) << 24) | (enc_t(b.w, thr) << 28);
}

// ---------------- Pass 2: quantize W -> packed fp4 (32 elems/thread) -----------
__global__ __launch_bounds__(256) void quantw_kernel(const float4* __restrict__ W4,
                                                     uint4* __restrict__ out,
                                                     const float* __restrict__ thrp) {
    float thr = *thrp;
    long gt = (long)blockIdx.x * 256 + threadIdx.x;
    uint32_t d0 = pack8(W4[gt * 8 + 0], W4[gt * 8 + 1], thr);
    uint32_t d1 = pack8(W4[gt * 8 + 2], W4[gt * 8 + 3], thr);
    uint32_t d2 = pack8(W4[gt * 8 + 4], W4[gt * 8 + 5], thr);
    uint32_t d3 = pack8(W4[gt * 8 + 6], W4[gt * 8 + 7], thr);
    out[gt] = make_uint4(d0, d1, d2, d3);
}

// ---------------- Pass 3: binarize x -> packed fp4 sign ------------------------
__global__ __launch_bounds__(256) void quantx_kernel(const float4* __restrict__ X4,
                                                     uint4* __restrict__ out) {
    long gt = (long)blockIdx.x * 256 + threadIdx.x;
    uint32_t d0 = pack8(X4[gt * 8 + 0], X4[gt * 8 + 1], 0.f);
    uint32_t d1 = pack8(X4[gt * 8 + 2], X4[gt * 8 + 3], 0.f);
    uint32_t d2 = pack8(X4[gt * 8 + 4], X4[gt * 8 + 5], 0.f);
    uint32_t d3 = pack8(X4[gt * 8 + 6], X4[gt * 8 + 7], 0.f);
    out[gt] = make_uint4(d0, d1, d2, d3);
}

// ---------------- Pass 4: fp4 GEMM, 256^2 tile, mfma_scale 32x32x64 ------------
// r10 geometry (16 waves x 64x64 output on a 256^2 tile) with the spill fix:
// __launch_bounds__(1024, 4) -- min 4 waves/EU -> unified reg budget 512/wave
// (r10's bare (1024) defaulted the allocator to 64 arch VGPRs -> 1.57 GB of
// scratch spill traffic, WRITE_SIZE 2.09 GB, MfmaUtil 12.9%).
// Need ~70 arch + 64 acc = ~134 << 512: no spills, still 16 waves/CU (4/SIMD)
// -> 4 independent instruction streams per SIMD: one wave's 4-MFMA cluster
// overlaps other waves' ds_read bursts (TLP; lockstep 2-waves/SIMD could not).
// Schedule identical to r9/r10 (proven absmax 0): unit = 16 KB operand K-tile,
// ring 8 slots, lead 5 units, single barrier per half-phase, counted vmcnt
// 3/2/0 (1 staging load per thread per unit at 1024 threads).
__global__ __launch_bounds__(1024, 4) void gemm_fp4(const uint8_t* __restrict__ A,
                                                    const uint8_t* __restrict__ B,
                                                    float* __restrict__ C) {
    __shared__ __align__(16) uint8_t smem[8 * 16384];   // 128 KiB

    const int t = threadIdx.x;
    const int l = t & 63;
    const int wid = t >> 6;           // 0..15
    const int wm = wid >> 2;          // 0..3
    const int wn = wid & 3;           // 0..3
    const int lr = l & 31;            // row within 32
    const int lh = l >> 5;            // k-chunk selector

    // Bijective XCD swizzle: 2048 wgs % 8 == 0.
    int wg = blockIdx.x;
    int sw = (wg & 7) * 256 + (wg >> 3);
    int bm = sw & 31;                 // 32 M-tiles
    int bn = sw >> 5;                 // 64 N-tiles
    const long m0 = (long)bm * 256;
    const long n0 = (long)bn * 256;

    // Staging: unit = 1024 chunks of 16B, thread t takes chunk t.
    // Phys chunk cp holds row r = cp>>2, logical col c = (cp&3)^((r>>1)&3).
    const int r0s = t >> 2;           // 0..255
    const int cb0 = (((t & 3) ^ ((r0s >> 1) & 3)) << 4);
    const int voff = r0s * KB + cb0;             // shared by A and B panels
    const uint8_t* Abase = A + m0 * (long)KB;    // uniform -> SGPR
    const uint8_t* Bbase = B + n0 * (long)KB;    // uniform -> SGPR
    const int lo = t * 16;

    // ds_read offsets (swizzled, r2-proven XOR), per k-half h: c = h*2 + lh.
    auto swz = [](int r, int c) {
        return r * 64 + ((c ^ ((r >> 1) & 3)) << 4);
    };
    int offA[2][2], offB[2][2];
#pragma unroll
    for (int h = 0; h < 2; ++h) {
#pragma unroll
        for (int mt = 0; mt < 2; ++mt)
            offA[h][mt] = swz(wm * 64 + mt * 32 + lr, h * 2 + lh);
#pragma unroll
        for (int nt = 0; nt < 2; ++nt)
            offB[h][nt] = swz(wn * 64 + nt * 32 + lr, h * 2 + lh);
    }

    v16f acc[2][2] = {};   // 64 regs (AGPR-eligible)

    // Prologue: issue units 0..4 (1 load each); wait units 0,1 landed.
#pragma unroll
    for (int j = 0; j < 5; ++j) {
        const uint8_t* s = (j & 1) ? Bbase : Abase;
        __builtin_amdgcn_global_load_lds(GLOBAL_AS(s + (j >> 1) * 64 + voff),
                                         LDS_AS(smem + j * 16384 + lo), 16, 0, 0);
    }
    asm volatile("s_waitcnt vmcnt(3)" ::: "memory");
    asm volatile("s_barrier" ::: "memory");

#pragma unroll 2
    for (int tau = 0; tau < 32; ++tau) {
        auto phase = [&](auto hc) {
            constexpr int h = decltype(hc)::value;
            const int sA = (2 * tau) & 7;
            const int sB = sA + 1;
            // Fragments in low half of v8i; high half undef (HW reads only
            // regs 0..3 for FMT=fp4 -- r4/r5/r6 exactness proves it).
            v8i a0, a1, b0, b1;
            {
                v4i v = *(const v4i*)(smem + sA * 16384 + offA[h][0]);
                a0 = __builtin_shufflevector(v, v, 0, 1, 2, 3, -1, -1, -1, -1);
            }
            {
                v4i v = *(const v4i*)(smem + sA * 16384 + offA[h][1]);
                a1 = __builtin_shufflevector(v, v, 0, 1, 2, 3, -1, -1, -1, -1);
            }
            {
                v4i v = *(const v4i*)(smem + sB * 16384 + offB[h][0]);
                b0 = __builtin_shufflevector(v, v, 0, 1, 2, 3, -1, -1, -1, -1);
            }
            {
                v4i v = *(const v4i*)(smem + sB * 16384 + offB[h][1]);
                b1 = __builtin_shufflevector(v, v, 0, 1, 2, 3, -1, -1, -1, -1);
            }
            // Stage unit j = 2*tau + h + 5 into slot j&7 (freed 2 barriers ago).
            {
                int j = 2 * tau + h + 5;
                if (j < 64) {
                    const uint8_t* s = (j & 1) ? Bbase : Abase;
                    __builtin_amdgcn_global_load_lds(GLOBAL_AS(s + (j >> 1) * 64 + voff),
                                                     LDS_AS(smem + (j & 7) * 16384 + lo), 16, 0, 0);
                }
            }
            __builtin_amdgcn_s_setprio(1);
            acc[0][0] = __builtin_amdgcn_mfma_scale_f32_32x32x64_f8f6f4(
                a0, b0, acc[0][0], 4, 4, 0, 0x7F7F7F7F, 0, 0x7F7F7F7F);
            acc[0][1] = __builtin_amdgcn_mfma_scale_f32_32x32x64_f8f6f4(
                a0, b1, acc[0][1], 4, 4, 0, 0x7F7F7F7F, 0, 0x7F7F7F7F);
            acc[1][0] = __builtin_amdgcn_mfma_scale_f32_32x32x64_f8f6f4(
                a1, b0, acc[1][0], 4, 4, 0, 0x7F7F7F7F, 0, 0x7F7F7F7F);
            acc[1][1] = __builtin_amdgcn_mfma_scale_f32_32x32x64_f8f6f4(
                a1, b1, acc[1][1], 4, 4, 0, 0x7F7F7F7F, 0, 0x7F7F7F7F);
            __builtin_amdgcn_s_setprio(0);
            if constexpr (h == 1) {
                if (tau <= 28)      asm volatile("s_waitcnt vmcnt(3)" ::: "memory");
                else if (tau == 29) asm volatile("s_waitcnt vmcnt(2)" ::: "memory");
                else if (tau == 30) asm volatile("s_waitcnt vmcnt(0)" ::: "memory");
            }
            asm volatile("s_barrier" ::: "memory");
        };
        phase(IC<0>{});
        phase(IC<1>{});
    }

    // Epilogue: 32x32 C/D layout col = lane&31, row = (reg&3)+8*(reg>>2)+4*(lane>>5).
#pragma unroll
    for (int mt = 0; mt < 2; ++mt) {
        long rbase = m0 + wm * 64 + mt * 32 + 4 * lh;
#pragma unroll
        for (int nt = 0; nt < 2; ++nt) {
            long gcol = n0 + wn * 64 + nt * 32 + lr;
#pragma unroll
            for (int r = 0; r < 16; ++r) {
                long grow = rbase + (r & 3) + 8 * (r >> 2);
                C[grow * Nx + gcol] = acc[mt][nt][r];
            }
        }
    }
}

extern "C" void kernel_launch(void* const* d_in, const int* in_sizes, int n_in,
                              void* d_out, int out_size, void* d_ws, size_t ws_size,
                              hipStream_t stream) {
    const float* x = (const float*)d_in[0];
    const float* weight = (const float*)d_in[1];
    float* out = (float*)d_out;

    // Workspace: xq 16 MB | wq 32 MB | partials 16 KB | thr
    uint8_t* xq = (uint8_t*)d_ws;
    uint8_t* wq = xq + X_ELEMS / 2;
    double* partials = (double*)((char*)d_ws + X_ELEMS / 2 + W_ELEMS / 2);
    float* thr = (float*)((char*)d_ws + X_ELEMS / 2 + W_ELEMS / 2 + 2048 * sizeof(double));

    absum_kernel<<<2048, 256, 0, stream>>>((const float4*)weight, partials);
    finalize_kernel<<<1, 256, 0, stream>>>(partials, thr);
    quantw_kernel<<<8192, 256, 0, stream>>>((const float4*)weight, (uint4*)wq, thr);
    quantx_kernel<<<4096, 256, 0, stream>>>((const float4*)x, (uint4*)xq);
    gemm_fp4<<<2048, 1024, 0, stream>>>(xq, wq, out);
}

// Round 12
// 563.632 us; speedup vs baseline: 1.8628x; 1.8612x over previous
//
#include <hip/hip_runtime.h>
#include <hip/hip_bf16.h>
#include <cstdint>

constexpr int Mx = 8192;
constexpr int Kx = 4096;
constexpr int Nx = 16384;
constexpr long W_ELEMS = (long)Nx * Kx;      // 67108864
constexpr long X_ELEMS = (long)Mx * Kx;      // 33554432
constexpr int KB = Kx / 2;                   // 2048 packed fp4 bytes per row

typedef int v4i __attribute__((ext_vector_type(4)));
typedef int v8i __attribute__((ext_vector_type(8)));
typedef float v16f __attribute__((ext_vector_type(16)));

#define GLOBAL_AS(p) ((const __attribute__((address_space(1))) void*)(p))
#define LDS_AS(p)    ((__attribute__((address_space(3))) void*)(p))

template <int P> struct IC { static constexpr int value = P; };

// ---------------- Pass 1: sum |W| (deterministic two-level tree) ----------------
__global__ __launch_bounds__(256) void absum_kernel(const float4* __restrict__ W4,
                                                    double* __restrict__ partials) {
    int t = threadIdx.x;
    long base = (long)blockIdx.x * 8192;
    double s = 0.0;
#pragma unroll 4
    for (int i = 0; i < 32; ++i) {
        float4 v = W4[base + (long)i * 256 + t];
        s += (double)fabsf(v.x) + (double)fabsf(v.y) +
             (double)fabsf(v.z) + (double)fabsf(v.w);
    }
    __shared__ double sm[256];
    sm[t] = s;
    __syncthreads();
    for (int off = 128; off > 0; off >>= 1) {
        if (t < off) sm[t] += sm[t + off];
        __syncthreads();
    }
    if (t == 0) partials[blockIdx.x] = sm[0];
}

__global__ __launch_bounds__(256) void finalize_kernel(const double* __restrict__ partials,
                                                       float* __restrict__ thr) {
    int t = threadIdx.x;
    double s = 0.0;
#pragma unroll
    for (int i = 0; i < 8; ++i) s += partials[(long)i * 256 + t];
    __shared__ double sm[256];
    sm[t] = s;
    __syncthreads();
    for (int off = 128; off > 0; off >>= 1) {
        if (t < off) sm[t] += sm[t + off];
        __syncthreads();
    }
    if (t == 0) {
        double gamma = sm[0] / (double)W_ELEMS + 1e-6;
        *thr = (float)(0.5 * gamma);
    }
}

// fp4 e2m1 encode of ternary: +1 -> 0x2, -1 -> 0xA, 0 -> 0x0
__device__ __forceinline__ uint32_t enc_t(float v, float thr) {
    return (fabsf(v) > thr) ? ((v > 0.f) ? 0x2u : 0xAu) : 0x0u;
}

__device__ __forceinline__ uint32_t pack8(float4 a, float4 b, float thr) {
    return enc_t(a.x, thr)        | (enc_t(a.y, thr) << 4)  |
          (enc_t(a.z, thr) << 8)  | (enc_t(a.w, thr) << 12) |
          (enc_t(b.x, thr) << 16) | (enc_t(b.y, thr) << 20) |
          (enc_t(b.z, thr) << 24) | (enc_t(b.w, thr) << 28);
}

// ---------------- Pass 2: quantize W -> packed fp4 -----------------------------
// Coalescing fix (G13): thread g owns 8 consecutive elements -> two float4
// loads at {2g, 2g+1} (stride-2 per instr; both halves of each 64B line used
// via L1 across the pair) + one fully-coalesced u32 store.  Grid-stride x4.
__global__ __launch_bounds__(256) void quantw_kernel(const float4* __restrict__ W4,
                                                     uint32_t* __restrict__ out,
                                                     const float* __restrict__ thrp) {
    float thr = *thrp;
    long g = (long)blockIdx.x * 1024 + threadIdx.x;   // 8192 blocks * 4 iters
#pragma unroll
    for (int i = 0; i < 4; ++i, g += 256) {
        float4 a = W4[2 * g];
        float4 b = W4[2 * g + 1];
        out[g] = pack8(a, b, thr);
    }
}

// ---------------- Pass 3: binarize x -> packed fp4 sign ------------------------
__global__ __launch_bounds__(256) void quantx_kernel(const float4* __restrict__ X4,
                                                     uint32_t* __restrict__ out) {
    long g = (long)blockIdx.x * 1024 + threadIdx.x;   // 4096 blocks * 4 iters
#pragma unroll
    for (int i = 0; i < 4; ++i, g += 256) {
        float4 a = X4[2 * g];
        float4 b = X4[2 * g + 1];
        out[g] = pack8(a, b, 0.f);
    }
}

// ---------------- Pass 4: fp4 GEMM, 256^2 tile, mfma_scale 32x32x64 ------------
// r9 kernel verbatim (proven 383 us, absmax 0, no spills: 124 arch + 128 acc).
// Single barrier per half-phase; unit = 16 KB operand K-tile; ring 8 slots;
// lead 5 units; counted vmcnt 6/4/0; r2-proven XOR swizzle (both-sides).
__global__ __launch_bounds__(512) void gemm_fp4(const uint8_t* __restrict__ A,
                                                const uint8_t* __restrict__ B,
                                                float* __restrict__ C) {
    __shared__ __align__(16) uint8_t smem[8 * 16384];   // 128 KiB

    const int t = threadIdx.x;
    const int l = t & 63;
    const int wid = t >> 6;
    const int wm = wid >> 2;          // 0..1
    const int wn = wid & 3;           // 0..3
    const int lr = l & 31;            // row within 32
    const int lh = l >> 5;            // k-chunk selector

    // Bijective XCD swizzle: 2048 wgs % 8 == 0.
    int wg = blockIdx.x;
    int sw = (wg & 7) * 256 + (wg >> 3);
    int bm = sw & 31;                 // 32 M-tiles
    int bn = sw >> 5;                 // 64 N-tiles
    const long m0 = (long)bm * 256;
    const long n0 = (long)bn * 256;

    // Staging: phys chunk cp holds row r = cp>>2, logical col c = (cp&3)^((r>>1)&3).
    // cp0 = t, cp1 = t+512 (row + 128: same XOR since 128 % 4 == 0).
    const int r0s = t >> 2;
    const int cb0 = (((t & 3) ^ ((r0s >> 1) & 3)) << 4);
    const int voff0 = r0s * KB + cb0;            // shared by A and B panels
    const int voff1 = voff0 + 128 * KB;
    const uint8_t* Abase = A + m0 * (long)KB;    // uniform -> SGPR
    const uint8_t* Bbase = B + n0 * (long)KB;    // uniform -> SGPR
    const int lo0 = t * 16, lo1 = t * 16 + 8192;

    // ds_read offsets (swizzled), per k-half h: c = h*2 + lh.
    auto swz = [](int r, int c) {
        return r * 64 + ((c ^ ((r >> 1) & 3)) << 4);
    };
    int offA[2][4], offB[2][2];
#pragma unroll
    for (int h = 0; h < 2; ++h) {
#pragma unroll
        for (int mt = 0; mt < 4; ++mt)
            offA[h][mt] = swz(wm * 128 + mt * 32 + lr, h * 2 + lh);
#pragma unroll
        for (int nt = 0; nt < 2; ++nt)
            offB[h][nt] = swz(wn * 64 + nt * 32 + lr, h * 2 + lh);
    }

    v16f acc[4][2] = {};   // 128 regs (AGPR-eligible)

    // Prologue: issue units 0..4; wait units 0,1 landed (10-4=6 outstanding).
#pragma unroll
    for (int j = 0; j < 5; ++j) {
        int tj = j >> 1, slot = j;
        const uint8_t* s = (j & 1) ? Bbase : Abase;
        __builtin_amdgcn_global_load_lds(GLOBAL_AS(s + tj * 64 + voff0), LDS_AS(smem + slot * 16384 + lo0), 16, 0, 0);
        __builtin_amdgcn_global_load_lds(GLOBAL_AS(s + tj * 64 + voff1), LDS_AS(smem + slot * 16384 + lo1), 16, 0, 0);
    }
    asm volatile("s_waitcnt vmcnt(6)" ::: "memory");
    asm volatile("s_barrier" ::: "memory");

#pragma unroll 2
    for (int tau = 0; tau < 32; ++tau) {
        auto phase = [&](auto hc) {
            constexpr int h = decltype(hc)::value;
            const int sA = (2 * tau) & 7;
            const int sB = sA + 1;
            // Fragments in low half of v8i; high half undef (HW reads only
            // regs 0..3 for FMT=fp4 -- r4/r5/r6 exactness proves it).
            v8i ar8[4], br8[2];
#pragma unroll
            for (int mt = 0; mt < 4; ++mt) {
                v4i v = *(const v4i*)(smem + sA * 16384 + offA[h][mt]);
                ar8[mt] = __builtin_shufflevector(v, v, 0, 1, 2, 3, -1, -1, -1, -1);
            }
#pragma unroll
            for (int nt = 0; nt < 2; ++nt) {
                v4i v = *(const v4i*)(smem + sB * 16384 + offB[h][nt]);
                br8[nt] = __builtin_shufflevector(v, v, 0, 1, 2, 3, -1, -1, -1, -1);
            }
            // Stage unit j = 2*tau + h + 5 into slot j&7 (freed at phase j-3).
            {
                int j = 2 * tau + h + 5;
                if (j < 64) {
                    int tj = j >> 1, slot = j & 7;
                    const uint8_t* s = (j & 1) ? Bbase : Abase;
                    __builtin_amdgcn_global_load_lds(GLOBAL_AS(s + tj * 64 + voff0), LDS_AS(smem + slot * 16384 + lo0), 16, 0, 0);
                    __builtin_amdgcn_global_load_lds(GLOBAL_AS(s + tj * 64 + voff1), LDS_AS(smem + slot * 16384 + lo1), 16, 0, 0);
                }
            }
            __builtin_amdgcn_s_setprio(1);
#pragma unroll
            for (int mt = 0; mt < 4; ++mt)
#pragma unroll
                for (int nt = 0; nt < 2; ++nt)
                    acc[mt][nt] = __builtin_amdgcn_mfma_scale_f32_32x32x64_f8f6f4(
                        ar8[mt], br8[nt], acc[mt][nt], 4, 4, 0, 0x7F7F7F7F, 0, 0x7F7F7F7F);
            __builtin_amdgcn_s_setprio(0);
            if constexpr (h == 1) {
                if (tau <= 28)      asm volatile("s_waitcnt vmcnt(6)" ::: "memory");
                else if (tau == 29) asm volatile("s_waitcnt vmcnt(4)" ::: "memory");
                else if (tau == 30) asm volatile("s_waitcnt vmcnt(0)" ::: "memory");
            }
            asm volatile("s_barrier" ::: "memory");   // B2
        };
        phase(IC<0>{});
        phase(IC<1>{});
    }

    // Epilogue: 32x32 C/D layout col = lane&31, row = (reg&3)+8*(reg>>2)+4*(lane>>5).
#pragma unroll
    for (int mt = 0; mt < 4; ++mt) {
        long rbase = m0 + wm * 128 + mt * 32 + 4 * lh;
#pragma unroll
        for (int nt = 0; nt < 2; ++nt) {
            long gcol = n0 + wn * 64 + nt * 32 + lr;
#pragma unroll
            for (int r = 0; r < 16; ++r) {
                long grow = rbase + (r & 3) + 8 * (r >> 2);
                C[grow * Nx + gcol] = acc[mt][nt][r];
            }
        }
    }
}

extern "C" void kernel_launch(void* const* d_in, const int* in_sizes, int n_in,
                              void* d_out, int out_size, void* d_ws, size_t ws_size,
                              hipStream_t stream) {
    const float* x = (const float*)d_in[0];
    const float* weight = (const float*)d_in[1];
    float* out = (float*)d_out;

    // Workspace: xq 16 MB | wq 32 MB | partials 16 KB | thr
    uint8_t* xq = (uint8_t*)d_ws;
    uint8_t* wq = xq + X_ELEMS / 2;
    double* partials = (double*)((char*)d_ws + X_ELEMS / 2 + W_ELEMS / 2);
    float* thr = (float*)((char*)d_ws + X_ELEMS / 2 + W_ELEMS / 2 + 2048 * sizeof(double));

    absum_kernel<<<2048, 256, 0, stream>>>((const float4*)weight, partials);
    finalize_kernel<<<1, 256, 0, stream>>>(partials, thr);
    quantw_kernel<<<8192, 256, 0, stream>>>((const float4*)weight, (uint32_t*)wq, thr);
    quantx_kernel<<<4096, 256, 0, stream>>>((const float4*)x, (uint32_t*)xq);
    gemm_fp4<<<2048, 512, 0, stream>>>(xq, wq, out);
}